// Round 2
// baseline (787.211 us; speedup 1.0000x reference)
//
#include <hip/hip_runtime.h>

#define DEV __device__ __forceinline__

typedef __attribute__((ext_vector_type(8))) short bf16x8;
typedef __attribute__((ext_vector_type(4))) short s16x4;
typedef __attribute__((ext_vector_type(4))) float f32x4;

constexpr int Dd = 64, Hh = 128, Tt = 1024, TLr = 1022;
constexpr int ROWS = 32;      // rows per workgroup
constexpr int NTHR = 512;     // 8 waves
constexpr int NTILE = 32;     // row tiles per batch element
constexpr long WSW_BYTES = 1015808;  // preconverted weight image bytes

#define MFMA16(a,b,c) __builtin_amdgcn_mfma_f32_16x16x32_bf16((a),(b),(c),0,0,0)

// global -> LDS direct copy, 16B per lane (preconverted, pre-swizzled image)
#define GLDS16(gp, lp) __builtin_amdgcn_global_load_lds( \
    (__attribute__((address_space(1))) void*)(void*)(gp), \
    (__attribute__((address_space(3))) void*)(void*)(lp), 16, 0, 0)

DEV short bf16hi(float f){
  unsigned u = __builtin_bit_cast(unsigned, f);
  u += 0x7FFFu + ((u >> 16) & 1u);          // round-to-nearest-even
  return (short)(u >> 16);
}
DEV float bf2f(short h){
  unsigned u = ((unsigned)(unsigned short)h) << 16;
  return __builtin_bit_cast(float, u);
}
DEV void splitbf(float f, short &h, short &l){
  h = bf16hi(f);
  l = bf16hi(f - bf2f(h));
}

// ACT: 0 none, 1 tanh, 2 relu, 3 leaky(0.2)
template<int A> DEV float actf(float x){
  if constexpr (A == 1){
    float e = __expf(2.f * x);
    return 1.f - 2.f * __builtin_amdgcn_rcpf(e + 1.f);
  } else if constexpr (A == 2){
    return fmaxf(x, 0.f);
  } else if constexpr (A == 3){
    return x >= 0.f ? x : 0.2f * x;
  }
  return x;
}

template<int BYTES>
DEV void pref(const char* __restrict__ wsW, long off, char* dst, int tid){
  #pragma unroll
  for (int it = 0; it < BYTES / 8192; ++it)
    GLDS16(wsW + off + it * 8192 + tid * 16, dst + it * 8192 + tid * 16);
}

// One layer: C^T = W(HOxHI) . Act^T over 32 rows. Each wave: 16 rows x (HO/4) feats.
// Act buffers: hi at +0, lo at +8192, row stride 256B, swizzle byte ^= (row&7)<<4.
// W buffer: hi at +0, lo at +HO*HI*2, row stride HI*2, swizzle byte ^= (feat&7)<<4.
template<int HI, int HO, int ACT, bool WOUT>
DEV void layerT(const char* aIn, char* aOut, const char* Wp,
                const float* __restrict__ bias,
                int w, int r16, int hi4, int rr, f32x4* outv)
{
  constexpr int LOFF = HO * HI * 2;
  constexpr int NKT = HI / 32;
  constexpr int NMT = HO / 64;          // 2 for HO=128, 1 for HO=64
  const int mtB = (w & 3) * NMT;
  const int swzR = (rr & 7) << 4;
  f32x4 acc[NMT];
  #pragma unroll
  for (int m = 0; m < NMT; ++m) acc[m] = (f32x4){0.f, 0.f, 0.f, 0.f};

  #pragma unroll
  for (int kt = 0; kt < NKT; ++kt){
    const int kOff = kt * 64 + hi4 * 16;
    const int byteB = (rr * 256 + kOff) ^ swzR;
    bf16x8 Bhv = *(const bf16x8*)(aIn + byteB);
    bf16x8 Blv = *(const bf16x8*)(aIn + 8192 + byteB);
    #pragma unroll
    for (int m = 0; m < NMT; ++m){
      const int feat = (mtB + m) * 16 + r16;
      const int byteA = (feat * (HI * 2) + kOff) ^ ((feat & 7) << 4);
      bf16x8 Ahv = *(const bf16x8*)(Wp + byteA);
      bf16x8 Alv = *(const bf16x8*)(Wp + LOFF + byteA);
      acc[m] = MFMA16(Ahv, Bhv, acc[m]);
      acc[m] = MFMA16(Ahv, Blv, acc[m]);
      acc[m] = MFMA16(Alv, Bhv, acc[m]);
    }
  }

  #pragma unroll
  for (int m = 0; m < NMT; ++m){
    const int fB = (mtB + m) * 16 + hi4 * 4;
    f32x4 bv = *(const f32x4*)(bias + fB);
    f32x4 v;
    #pragma unroll
    for (int j = 0; j < 4; ++j) v[j] = actf<ACT>(acc[m][j] + bv[j]);
    if constexpr (WOUT){
      s16x4 hv, lv;
      #pragma unroll
      for (int j = 0; j < 4; ++j){ short h, l; splitbf(v[j], h, l); hv[j] = h; lv[j] = l; }
      const int byteC = (rr * 256 + fB * 2) ^ swzR;
      *(s16x4*)(aOut + byteC) = hv;
      *(s16x4*)(aOut + 8192 + byteC) = lv;
    } else {
      outv[m] = v;
    }
  }
}

// Rebuild masked coupling input mx = u*m (features fB..fB+3 of row rr).
DEV void buildMx(char* a, const f32x4& u, int keep, int rr, int fB){
  s16x4 hv, lv;
  #pragma unroll
  for (int j = 0; j < 4; ++j){
    float val = ((j & 1) == keep) ? u[j] : 0.f;   // feature parity == j parity (fB mult of 4)
    short h, l; splitbf(val, h, l); hv[j] = h; lv[j] = l;
  }
  const int byteC = (rr * 256 + fB * 2) ^ ((rr & 7) << 4);
  *(s16x4*)(a + byteC) = hv;
  *(s16x4*)(a + 8192 + byteC) = lv;
}

// f1 window input: win[r] = concat(x[t0+r], x[t0+r+1]) -> 128 features.
DEV void buildWin(char* a, const float* __restrict__ xb, int t0, int tid){
  const int rr = tid >> 4;                // 0..31
  const int fg = (tid & 15) << 3;         // 0,8,...,120
  int xr = t0 + rr + (fg >= 64 ? 1 : 0);
  if (xr > Tt - 1) xr = Tt - 1;           // clamp; rows past TLr are discarded
  const int fo = fg & 63;
  const f32x4* p = (const f32x4*)(xb + xr * Dd + fo);
  f32x4 v0 = p[0], v1 = p[1];
  bf16x8 h8, l8;
  #pragma unroll
  for (int j = 0; j < 4; ++j){
    short h, l;
    splitbf(v0[j], h, l); h8[j] = h;     l8[j] = l;
    splitbf(v1[j], h, l); h8[4 + j] = h; l8[4 + j] = l;
  }
  const int byteC = (rr * 256 + fg * 2) ^ ((rr & 7) << 4);
  *(bf16x8*)(a + byteC) = h8;
  *(bf16x8*)(a + 8192 + byteC) = l8;
}

// ---- Weight preconversion: fp32 -> swizzled LDS-image bf16 hi/lo in d_ws ----
// Layer image = [hi HO*HI*2 B][lo HO*HI*2 B]; per-flow-block span 262144 B:
//   s0 @+0(32768) s1 @+32768(65536) s2 @+98304(32768)
//   t0 @+131072(32768) t1 @+163840(65536) t2 @+229376(32768)
// f1: hW_i @786432+i*65536, oW @983040(32768). Total 1015808 B.
__global__ void pnl_conv(const float* __restrict__ sW0, const float* __restrict__ sW1,
                         const float* __restrict__ sW2, const float* __restrict__ tW0,
                         const float* __restrict__ tW1, const float* __restrict__ tW2,
                         const float* __restrict__ f1_hW, const float* __restrict__ f1_oW,
                         char* __restrict__ wsW)
{
  const int e = (blockIdx.x * 256 + threadIdx.x) * 4;
  const int chunk = e >> 13;        // 8192-element chunks
  const int eInC = e & 8191;
  const float* src; int hiShift; long dstBase; int eInL; int loOff;
  if (chunk < 24){
    const int blk = chunk >> 3, c8 = chunk & 7;
    dstBase = (long)blk * 262144;
    if (c8 == 0)      { src = sW0 + blk*8192;  hiShift = 6; eInL = eInC;                                  loOff = 16384; }
    else if (c8 <= 2) { src = sW1 + blk*16384; hiShift = 7; eInL = eInC + (c8-1)*8192; dstBase += 32768;  loOff = 32768; }
    else if (c8 == 3) { src = sW2 + blk*8192;  hiShift = 7; eInL = eInC;               dstBase += 98304;  loOff = 16384; }
    else if (c8 == 4) { src = tW0 + blk*8192;  hiShift = 6; eInL = eInC;               dstBase += 131072; loOff = 16384; }
    else if (c8 <= 6) { src = tW1 + blk*16384; hiShift = 7; eInL = eInC + (c8-5)*8192; dstBase += 163840; loOff = 32768; }
    else              { src = tW2 + blk*8192;  hiShift = 7; eInL = eInC;               dstBase += 229376; loOff = 16384; }
  } else if (chunk < 30){
    const int l = (chunk - 24) >> 1;
    src = f1_hW + l*16384; hiShift = 7; eInL = eInC + ((chunk-24)&1)*8192;
    dstBase = 786432 + (long)l*65536; loOff = 32768;
  } else {
    src = f1_oW; hiShift = 7; eInL = eInC; dstBase = 983040; loOff = 16384;
  }
  const int feat = eInL >> hiShift;
  const int k = eInL & ((1 << hiShift) - 1);
  f32x4 v = *(const f32x4*)(src + eInL);
  s16x4 hv, lv;
  #pragma unroll
  for (int j = 0; j < 4; ++j){ short h, l; splitbf(v[j], h, l); hv[j] = h; lv[j] = l; }
  const int off = ((feat << (hiShift + 1)) + (k << 1)) ^ ((feat & 7) << 4);
  *(s16x4*)(wsW + dstBase + off) = hv;
  *(s16x4*)(wsW + dstBase + loOff + off) = lv;
}

__global__ __launch_bounds__(NTHR, 2)
void pnl_main(const float* __restrict__ x,
              const float* __restrict__ f1_hb, const float* __restrict__ f1_ob,
              const float* __restrict__ sb0, const float* __restrict__ sb1,
              const float* __restrict__ sb2, const float* __restrict__ tb0,
              const float* __restrict__ tb1, const float* __restrict__ tb2,
              const char* __restrict__ wsW,
              float* __restrict__ resid, float* __restrict__ wsPart)
{
  __shared__ __align__(16) char Wb[2][65536];   // weight double buffer (hi|lo image)
  __shared__ __align__(16) char ab[2][16384];   // act ping-pong (hi @0, lo @8192)

  const int tid = threadIdx.x;
  const int w = tid >> 6, lane = tid & 63;
  const int r16 = lane & 15, hi4 = lane >> 4;
  const int rr = (w >> 2) * 16 + r16;          // this thread's row (0..31)
  const int fB = (w & 3) * 16 + hi4 * 4;       // small-layer feature base (0..60)
  const int bIdx = blockIdx.x >> 5;
  const int t0 = (blockIdx.x & 31) * ROWS;
  const float* xb = x + (long)bIdx * Tt * Dd;

  pref<32768>(wsW, 0, Wb[0], tid);             // sW0[0], earliest

  int xr = t0 + 2 + rr; if (xr > Tt - 1) xr = Tt - 1;
  f32x4 u = *(const f32x4*)(xb + xr * Dd + fB);
  float ld = 0.f;
  f32x4 sA[1], tA[1];

  buildMx(ab[0], u, 1, rr, fB);                // blk0 keeps odd features

  for (int blk = 0; blk < 3; ++blk){
    const long base = (long)blk * 262144;
    const int keep = 1 - (blk & 1);
    __syncthreads();
    pref<65536>(wsW, base + 32768, Wb[1], tid);                 // sW1
    layerT<64,128,1,true >(ab[0], ab[1], Wb[0], sb0 + blk*Hh, w, r16, hi4, rr, nullptr);
    __syncthreads();
    pref<32768>(wsW, base + 98304, Wb[0], tid);                 // sW2
    layerT<128,128,1,true >(ab[1], ab[0], Wb[1], sb1 + blk*Hh, w, r16, hi4, rr, nullptr);
    __syncthreads();
    pref<32768>(wsW, base + 131072, Wb[1], tid);                // tW0
    layerT<128,64,0,false>(ab[0], nullptr, Wb[0], sb2 + blk*Dd, w, r16, hi4, rr, sA);
    buildMx(ab[1], u, keep, rr, fB);
    __syncthreads();
    pref<65536>(wsW, base + 163840, Wb[0], tid);                // tW1
    layerT<64,128,2,true >(ab[1], ab[0], Wb[1], tb0 + blk*Hh, w, r16, hi4, rr, nullptr);
    __syncthreads();
    pref<32768>(wsW, base + 229376, Wb[1], tid);                // tW2
    layerT<128,128,2,true >(ab[0], ab[1], Wb[0], tb1 + blk*Hh, w, r16, hi4, rr, nullptr);
    __syncthreads();
    if (blk < 2) pref<32768>(wsW, base + 262144, Wb[0], tid);   // next sW0
    else         pref<65536>(wsW, 786432,        Wb[0], tid);   // f1_hW0
    layerT<128,64,0,false>(ab[1], nullptr, Wb[1], tb2 + blk*Dd, w, r16, hi4, rr, tA);

    #pragma unroll
    for (int j = 0; j < 4; ++j){
      if ((j & 1) != keep){
        float e = __expf(-sA[0][j]);
        u[j] = (u[j] - tA[0][j]) * e;
        ld -= sA[0][j];
      }
    }
    if (blk < 2) buildMx(ab[0], u, 1 - ((blk + 1) & 1), rr, fB);
    else         buildWin(ab[0], xb, t0, tid);
  }

  __syncthreads();
  pref<65536>(wsW, 786432 + 65536, Wb[1], tid);                 // f1_hW1
  layerT<128,128,3,true >(ab[0], ab[1], Wb[0], f1_hb,        w, r16, hi4, rr, nullptr);
  __syncthreads();
  pref<65536>(wsW, 786432 + 131072, Wb[0], tid);                // f1_hW2
  layerT<128,128,3,true >(ab[1], ab[0], Wb[1], f1_hb + Hh,   w, r16, hi4, rr, nullptr);
  __syncthreads();
  pref<32768>(wsW, 983040, Wb[1], tid);                         // f1_oW
  layerT<128,128,3,true >(ab[0], ab[1], Wb[0], f1_hb + 2*Hh, w, r16, hi4, rr, nullptr);
  __syncthreads();
  float* ldetS = (float*)ab[0];               // ab[0] dead after f1L2 read it
  if (tid < ROWS) ldetS[tid] = 0.f;
  f32x4 oA[1];
  layerT<128,64,0,false>(ab[1], nullptr, Wb[1], f1_ob, w, r16, hi4, rr, oA);

  const int tau = t0 + rr;
  if (tau < TLr){
    f32x4 st;
    #pragma unroll
    for (int j = 0; j < 4; ++j) st[j] = oA[0][j] - u[j];
    *(f32x4*)(resid + ((long)bIdx * TLr + tau) * Dd + fB) = st;
  }

  // logdet: shfl over the 4 k-group lanes, LDS atomics over the 4 feature-split waves
  float v = ld;
  v += __shfl_xor(v, 16);
  v += __shfl_xor(v, 32);
  __syncthreads();                             // zeroing + f1L2 reads complete
  if (hi4 == 0) atomicAdd(&ldetS[rr], v);
  __syncthreads();
  if (w == 0){
    float s = (lane < ROWS && (t0 + lane) < TLr) ? ldetS[lane] : 0.f;
    #pragma unroll
    for (int off = 1; off < 64; off <<= 1) s += __shfl_xor(s, off);
    if (lane == 0) wsPart[blockIdx.x] = s;
  }
}

// Deterministic final reduce: 32 tile-partials per batch element.
__global__ void pnl_ldet(const float* __restrict__ ws, float* __restrict__ outLd){
  const int b = threadIdx.x;
  float s = 0.f;
  #pragma unroll
  for (int t = 0; t < NTILE; ++t) s += ws[b * NTILE + t];
  outLd[b] = s;
}

extern "C" void kernel_launch(void* const* d_in, const int* in_sizes, int n_in,
                              void* d_out, int out_size, void* d_ws, size_t ws_size,
                              hipStream_t stream){
  const float* x     = (const float*)d_in[0];
  const float* f1_hW = (const float*)d_in[1];
  const float* f1_hb = (const float*)d_in[2];
  const float* f1_oW = (const float*)d_in[3];
  const float* f1_ob = (const float*)d_in[4];
  const float* sW0   = (const float*)d_in[5];
  const float* sb0   = (const float*)d_in[6];
  const float* sW1   = (const float*)d_in[7];
  const float* sb1   = (const float*)d_in[8];
  const float* sW2   = (const float*)d_in[9];
  const float* sb2   = (const float*)d_in[10];
  const float* tW0   = (const float*)d_in[11];
  const float* tb0   = (const float*)d_in[12];
  const float* tW1   = (const float*)d_in[13];
  const float* tb1   = (const float*)d_in[14];
  const float* tW2   = (const float*)d_in[15];
  const float* tb2   = (const float*)d_in[16];

  char*  wsW    = (char*)d_ws;
  float* wsPart = (float*)(wsW + WSW_BYTES);           // 8192 floats
  float* resid  = (float*)d_out;
  float* outLd  = resid + (long)256 * TLr * Dd;

  pnl_conv<<<dim3(248), dim3(256), 0, stream>>>(sW0, sW1, sW2, tW0, tW1, tW2,
                                                f1_hW, f1_oW, wsW);
  pnl_main<<<dim3(256 * NTILE), dim3(NTHR), 0, stream>>>(
      x, f1_hb, f1_ob, sb0, sb1, sb2, tb0, tb1, tb2, wsW, resid, wsPart);
  pnl_ldet<<<dim3(1), dim3(256), 0, stream>>>(wsPart, outLd);
}

// Round 3
// 462.326 us; speedup vs baseline: 1.7027x; 1.7027x over previous
//
#include <hip/hip_runtime.h>

#define DEV __device__ __forceinline__

typedef __attribute__((ext_vector_type(8)))  short bf16x8;
typedef __attribute__((ext_vector_type(4)))  short s16x4;
typedef __attribute__((ext_vector_type(4)))  float f32x4;
typedef __attribute__((ext_vector_type(16))) float f32x16;

constexpr int Dd = 64, Tt = 1024, TLr = 1022;
constexpr int NTHR = 512;            // 8 waves
constexpr int NTILE = 16;            // 64-row tiles per batch element
constexpr long WSW_BYTES = 1015808;  // preconverted weight image bytes

#define MFMA32(a,b,c) __builtin_amdgcn_mfma_f32_32x32x16_bf16((a),(b),(c),0,0,0)
#define MFMA16(a,b,c) __builtin_amdgcn_mfma_f32_16x16x32_bf16((a),(b),(c),0,0,0)

#define GLDS16(gp, lp) __builtin_amdgcn_global_load_lds( \
    (__attribute__((address_space(1))) void*)(void*)(gp), \
    (__attribute__((address_space(3))) void*)(void*)(lp), 16, 0, 0)

DEV short bf16hi(float f){
  unsigned u = __builtin_bit_cast(unsigned, f);
  u += 0x7FFFu + ((u >> 16) & 1u);
  return (short)(u >> 16);
}
DEV float bf2f(short h){
  unsigned u = ((unsigned)(unsigned short)h) << 16;
  return __builtin_bit_cast(float, u);
}
DEV void splitbf(float f, short &h, short &l){
  h = bf16hi(f);
  l = bf16hi(f - bf2f(h));
}

// ACT: 0 none, 1 tanh, 2 relu, 3 leaky(0.2)
template<int A> DEV float actf(float x){
  if constexpr (A == 1){
    float e = __expf(2.f * x);
    return 1.f - 2.f * __builtin_amdgcn_rcpf(e + 1.f);
  } else if constexpr (A == 2){
    return fmaxf(x, 0.f);
  } else if constexpr (A == 3){
    return x >= 0.f ? x : 0.2f * x;
  }
  return x;
}

template<int BYTES>
DEV void pref(const char* __restrict__ wsW, long off, char* dst, int tid){
  #pragma unroll
  for (int it = 0; it < BYTES / 8192; ++it)
    GLDS16(wsW + off + it * 8192 + tid * 16, dst + it * 8192 + tid * 16);
}

// Big layer (HO=128), 32x32x16 MFMA, 64 rows. Waves: featg=(w&3) x rowg=(w>>2).
// Weights: fragment-linear image, block (kt*4+m)*2048, hi@+0 lo@+1024.
// Acts: [row][feat] bf16, stride HI*2 in, 256 out, swizzle byte^=(row&7)<<4.
template<int HI, int ACT>
DEV void layer32(const char* __restrict__ aIn, char* __restrict__ aOut,
                 const char* __restrict__ Wp, const float* __restrict__ bias,
                 int w, int lane)
{
  constexpr int NKT = HI / 16;
  constexpr int STR = HI * 2;
  const int row = ((w >> 2) << 5) + (lane & 31);
  const int swz = (row & 7) << 4;
  const int m   = w & 3;
  const int kcB = (lane >> 5) << 4;
  f32x16 acc;
  #pragma unroll
  for (int i = 0; i < 16; ++i) acc[i] = 0.f;

  #pragma unroll
  for (int kt = 0; kt < NKT; ++kt){
    const int byteB = (row * STR + kt * 32 + kcB) ^ swz;
    bf16x8 B = *(const bf16x8*)(aIn + byteB);
    const char* wp = Wp + (kt * 4 + m) * 2048 + lane * 16;
    bf16x8 Ah = *(const bf16x8*)(wp);
    bf16x8 Al = *(const bf16x8*)(wp + 1024);
    acc = MFMA32(Ah, B, acc);
    acc = MFMA32(Al, B, acc);
  }

  const int featB = m * 32 + ((lane >> 5) << 2);
  #pragma unroll
  for (int c = 0; c < 4; ++c){
    f32x4 bv = *(const f32x4*)(bias + featB + 8 * c);
    s16x4 hv;
    #pragma unroll
    for (int j = 0; j < 4; ++j){
      float v = actf<ACT>(acc[4 * c + j] + bv[j]);
      hv[j] = bf16hi(v);
    }
    const int byteC = (row * 256 + (featB + 8 * c) * 2) ^ swz;
    *(s16x4*)(aOut + byteC) = hv;
  }
}

// Small/16x16 layer (HI=128). OUT: 0 bf16 act store, 1 f32 store, 2 regs.
template<int ACT, int NT, int OUT, int NM>
DEV void layer16(const char* __restrict__ aIn, char* __restrict__ aOut,
                 const char* __restrict__ Wp, const float* __restrict__ bias,
                 int m, int row0, int lane, f32x4* outReg)
{
  const int r16 = lane & 15, kc = lane >> 4;
  f32x4 acc[NT];
  #pragma unroll
  for (int n = 0; n < NT; ++n)
    #pragma unroll
    for (int j = 0; j < 4; ++j) acc[n][j] = 0.f;

  #pragma unroll
  for (int kt = 0; kt < 4; ++kt){
    const char* wp = Wp + (kt * NM + m) * 2048 + lane * 16;
    bf16x8 Ah = *(const bf16x8*)(wp);
    bf16x8 Al = *(const bf16x8*)(wp + 1024);
    #pragma unroll
    for (int n = 0; n < NT; ++n){
      const int row = row0 + n * 16 + r16;
      const int byteB = (row * 256 + kt * 64 + kc * 16) ^ ((row & 7) << 4);
      bf16x8 B = *(const bf16x8*)(aIn + byteB);
      acc[n] = MFMA16(Ah, B, acc[n]);
      acc[n] = MFMA16(Al, B, acc[n]);
    }
  }

  const int fB = m * 16 + kc * 4;
  f32x4 bv = *(const f32x4*)(bias + fB);
  #pragma unroll
  for (int n = 0; n < NT; ++n){
    f32x4 v;
    #pragma unroll
    for (int j = 0; j < 4; ++j) v[j] = actf<ACT>(acc[n][j] + bv[j]);
    const int row = row0 + n * 16 + r16;
    if constexpr (OUT == 0){
      s16x4 hv;
      #pragma unroll
      for (int j = 0; j < 4; ++j) hv[j] = bf16hi(v[j]);
      const int byteC = (row * 256 + fB * 2) ^ ((row & 7) << 4);
      *(s16x4*)(aOut + byteC) = hv;
    } else if constexpr (OUT == 1){
      const int byteC = (row * 256 + fB * 4) ^ ((row & 7) << 4);
      *(f32x4*)(aOut + byteC) = v;
    } else {
      outReg[n] = v;
    }
  }
}

// mx = u*m into 128B-stride buffer (64 feats), single bf16.
DEV void buildMx(char* a, const f32x4 u[2], int keep, int w, int lane){
  const int fB = ((w & 3) << 4) + ((lane >> 4) << 2);
  #pragma unroll
  for (int n = 0; n < 2; ++n){
    const int row = ((w >> 2) << 5) + n * 16 + (lane & 15);
    s16x4 hv;
    #pragma unroll
    for (int j = 0; j < 4; ++j)
      hv[j] = bf16hi(((j & 1) == keep) ? u[n][j] : 0.f);
    const int byte = (row * 128 + fB * 2) ^ ((row & 7) << 4);
    *(s16x4*)(a + byte) = hv;
  }
}

// f1 window input (32 rows x 128 feats): win[r] = concat(x[t0h+r], x[t0h+r+1])
DEV void buildWin(char* a, const float* __restrict__ xb, int t0h, int tid){
  const int row = tid >> 4;
  const int fc  = (tid & 15) << 3;
  int xr = t0h + row + (fc >= 64 ? 1 : 0);
  if (xr > Tt - 1) xr = Tt - 1;
  const f32x4* p = (const f32x4*)(xb + xr * Dd + (fc & 63));
  f32x4 v0 = p[0], v1 = p[1];
  bf16x8 h8;
  #pragma unroll
  for (int j = 0; j < 4; ++j){
    h8[j]     = bf16hi(v0[j]);
    h8[4 + j] = bf16hi(v1[j]);
  }
  const int byte = (row * 256 + fc * 2) ^ ((row & 7) << 4);
  *(bf16x8*)(a + byte) = h8;
}

// ---- Weight preconversion: fp32 -> fragment-linear bf16 hi/lo images ----
__global__ void pnl_conv(const float* __restrict__ sW0, const float* __restrict__ sW1,
                         const float* __restrict__ sW2, const float* __restrict__ tW0,
                         const float* __restrict__ tW1, const float* __restrict__ tW2,
                         const float* __restrict__ f1_hW, const float* __restrict__ f1_oW,
                         char* __restrict__ wsW)
{
  const int cid = blockIdx.x * 256 + threadIdx.x;   // 0..31743
  const float* src; long dst; int hiShift; bool t16; int NM; int e;
  if (cid < 24576){
    const int blk = cid >> 13, r = cid & 8191;
    dst = (long)blk * 262144;
    if (r < 1024)      { src = sW0 + blk * 8192;  hiShift = 6; t16 = false; NM = 4; e = r; }
    else if (r < 3072) { src = sW1 + blk * 16384; hiShift = 7; t16 = false; NM = 4; e = r - 1024; dst += 32768; }
    else if (r < 4096) { src = sW2 + blk * 8192;  hiShift = 7; t16 = true;  NM = 4; e = r - 3072; dst += 98304; }
    else if (r < 5120) { src = tW0 + blk * 8192;  hiShift = 6; t16 = false; NM = 4; e = r - 4096; dst += 131072; }
    else if (r < 7168) { src = tW1 + blk * 16384; hiShift = 7; t16 = false; NM = 4; e = r - 5120; dst += 163840; }
    else               { src = tW2 + blk * 8192;  hiShift = 7; t16 = true;  NM = 4; e = r - 7168; dst += 229376; }
  } else {
    const int r = cid - 24576;
    if (r < 6144){ const int l = r >> 11; src = f1_hW + l * 16384; hiShift = 7; t16 = true; NM = 8; e = r & 2047; dst = 786432 + (long)l * 65536; }
    else         { src = f1_oW; hiShift = 7; t16 = true; NM = 4; e = r - 6144; dst = 983040; }
  }
  const int feat = e >> (hiShift - 3);
  const int k    = (e & ((1 << (hiShift - 3)) - 1)) << 3;
  int m, kt, lane;
  if (t16){ m = feat >> 4; kt = k >> 5; lane = (feat & 15) | (((k >> 3) & 3) << 4); }
  else    { m = feat >> 5; kt = k >> 4; lane = (feat & 31) | (((k >> 3) & 1) << 5); }
  const long off = dst + (long)((kt * NM + m) * 2048 + lane * 16);
  const float* sp = src + (feat << hiShift) + k;
  f32x4 v0 = *(const f32x4*)sp, v1 = *(const f32x4*)(sp + 4);
  s16x4 h0, h1, l0, l1;
  #pragma unroll
  for (int j = 0; j < 4; ++j){
    short hh, ll;
    splitbf(v0[j], hh, ll); h0[j] = hh; l0[j] = ll;
    splitbf(v1[j], hh, ll); h1[j] = hh; l1[j] = ll;
  }
  *(s16x4*)(wsW + off)           = h0;
  *(s16x4*)(wsW + off + 8)       = h1;
  *(s16x4*)(wsW + off + 1024)    = l0;
  *(s16x4*)(wsW + off + 1024 + 8)= l1;
}

__global__ __launch_bounds__(NTHR, 2)
void pnl_main(const float* __restrict__ x,
              const float* __restrict__ f1_hb, const float* __restrict__ f1_ob,
              const float* __restrict__ sb0, const float* __restrict__ sb1,
              const float* __restrict__ sb2, const float* __restrict__ tb0,
              const float* __restrict__ tb1, const float* __restrict__ tb2,
              const char* __restrict__ wsW,
              float* __restrict__ resid, float* __restrict__ wsPart)
{
  __shared__ __align__(16) char r0[65536];
  __shared__ __align__(16) char r1[65536];
  __shared__ __align__(16) char r2[32768];
  char* r0a = r0;
  char* r0b = r0 + 32768;
  char* A   = r2;            // flow: mx/h slot A ; f1: win@+0, hA@+8192
  char* Bb  = r2 + 16384;    // flow: h slot B    ; f1: hB@+0, F(f32)@+8192

  const int tid = threadIdx.x, w = tid >> 6, lane = tid & 63;
  const int bIdx = blockIdx.x >> 4;
  const int t0   = (blockIdx.x & 15) << 6;
  const float* xb = x + (long)bIdx * Tt * Dd;

  pref<32768>(wsW, 0, r0a, tid);        // s0 blk0
  pref<65536>(wsW, 32768, r1, tid);     // s1 blk0

  const int fB = ((w & 3) << 4) + ((lane >> 4) << 2);
  f32x4 u[2];
  #pragma unroll
  for (int n = 0; n < 2; ++n){
    int xr = t0 + 2 + ((w >> 2) << 5) + n * 16 + (lane & 15);
    if (xr > Tt - 1) xr = Tt - 1;
    u[n] = *(const f32x4*)(xb + xr * Dd + fB);
  }
  float ld0 = 0.f, ld1 = 0.f;
  f32x4 sA[2], tA[2];

  buildMx(A, u, 1, w, lane);            // blk0 keeps odd feats
  __syncthreads();

  for (int blk = 0; blk < 3; ++blk){
    const long base = (long)blk * 262144;
    const int keep = 1 - (blk & 1);

    // s0 [W r0a]: A(mx) -> Bb ; stage s2 -> r0b
    pref<32768>(wsW, base + 98304, r0b, tid);
    layer32<64, 1>(A, Bb, r0a, sb0 + blk * 128, w, lane);
    __syncthreads();

    // s1 [W r1]: Bb -> A ; stage t0 -> r0a
    pref<32768>(wsW, base + 131072, r0a, tid);
    layer32<128, 1>(Bb, A, r1, sb1 + blk * 128, w, lane);
    __syncthreads();

    // s2 [W r0b]: A -> sA ; stage t1 -> r1 ; rebuild mx -> Bb
    pref<65536>(wsW, base + 163840, r1, tid);
    layer16<0, 2, 2, 4>(A, nullptr, r0b, sb2 + blk * 64, w & 3, (w >> 2) << 5, lane, sA);
    buildMx(Bb, u, keep, w, lane);
    __syncthreads();

    // t0 [W r0a]: Bb(mx) -> A ; stage t2 -> r0b
    pref<32768>(wsW, base + 229376, r0b, tid);
    layer32<64, 2>(Bb, A, r0a, tb0 + blk * 128, w, lane);
    __syncthreads();

    // t1 [W r1]: A -> Bb ; stage next s0 -> r0a
    if (blk < 2) pref<32768>(wsW, base + 262144, r0a, tid);
    layer32<128, 2>(A, Bb, r1, tb1 + blk * 128, w, lane);
    __syncthreads();

    // t2 [W r0b]: Bb -> tA ; stage next s1 or f1h0 -> r1 ; buildWin at blk2
    if (blk < 2) pref<65536>(wsW, base + 262144 + 32768, r1, tid);
    else         pref<65536>(wsW, 786432, r1, tid);
    layer16<0, 2, 2, 4>(Bb, nullptr, r0b, tb2 + blk * 64, w & 3, (w >> 2) << 5, lane, tA);
    if (blk == 2) buildWin(A, xb, t0, tid);
    __syncthreads();

    // coupling update (registers): updated feats have parity != keep
    #pragma unroll
    for (int n = 0; n < 2; ++n)
      #pragma unroll
      for (int j = 0; j < 4; ++j)
        if ((j & 1) != keep){
          float e = __expf(-sA[n][j]);
          u[n][j] = (u[n][j] - tA[n][j]) * e;
          if (n == 0) ld0 -= sA[n][j]; else ld1 -= sA[n][j];
        }

    if (blk < 2){
      buildMx(A, u, 1 - ((blk + 1) & 1), w, lane);
      __syncthreads();
    }
  }

  // ---- f1 phase: two 32-row half-passes ----
  char* WIN = A;              // [0,8K)
  char* HA  = A + 8192;       // [8K,16K)
  char* HB  = Bb;             // [16K,24K)
  char* Fb  = Bb + 8192;      // [24K,32K) f32 outputs

  #pragma unroll 1
  for (int half = 0; half < 2; ++half){
    // h0 [W r1]: WIN -> HA ; stage h1 -> r0 (full)
    pref<65536>(wsW, 786432 + 65536, r0, tid);
    layer16<3, 2, 0, 8>(WIN, HA, r1, f1_hb, w, 0, lane, nullptr);
    __syncthreads();

    // h1 [W r0]: HA -> HB ; stage h2 -> r1
    pref<65536>(wsW, 786432 + 131072, r1, tid);
    layer16<3, 2, 0, 8>(HA, HB, r0, f1_hb + 128, w, 0, lane, nullptr);
    __syncthreads();

    // h2 [W r1]: HB -> HA ; stage f1o -> r0a
    pref<32768>(wsW, 983040, r0a, tid);
    layer16<3, 2, 0, 8>(HB, HA, r1, f1_hb + 256, w, 0, lane, nullptr);
    __syncthreads();

    // f1o [W r0a]: HA -> Fb (f32) ; stage next-half h0 -> r1 ; build next win
    if (half == 0) pref<65536>(wsW, 786432, r1, tid);
    layer16<0, 1, 1, 4>(HA, Fb, r0a, f1_ob, w & 3, (w >> 2) << 4, lane, nullptr);
    if (half == 0) buildWin(WIN, xb, t0 + 32, tid);
    __syncthreads();

    // epilogue: waves whose u-rows live in this half
    if ((w >> 2) == half){
      #pragma unroll
      for (int n = 0; n < 2; ++n){
        const int rloc = n * 16 + (lane & 15);
        const int byte = (rloc * 256 + fB * 4) ^ ((rloc & 7) << 4);
        f32x4 fv = *(const f32x4*)(Fb + byte);
        const int tau = t0 + half * 32 + rloc;
        if (tau < TLr){
          f32x4 st;
          #pragma unroll
          for (int j = 0; j < 4; ++j) st[j] = fv[j] - u[n][j];
          *(f32x4*)(resid + ((long)bIdx * TLr + tau) * Dd + fB) = st;
        }
      }
    }
  }

  // ---- logdet: pure-shuffle reduce -> 8 floats per wg ----
  const int R0 = t0 + ((w >> 2) << 5) + (lane & 15);
  float a0 = (R0 < TLr) ? ld0 : 0.f;
  float a1 = (R0 + 16 < TLr) ? ld1 : 0.f;
  a0 += __shfl_xor(a0, 16); a0 += __shfl_xor(a0, 32);
  a1 += __shfl_xor(a1, 16); a1 += __shfl_xor(a1, 32);
  float s = a0 + a1;                     // lanes 0-15 hold distinct rows
  s += __shfl_xor(s, 1); s += __shfl_xor(s, 2);
  s += __shfl_xor(s, 4); s += __shfl_xor(s, 8);
  if (lane == 0) wsPart[blockIdx.x * 8 + w] = s;
}

// Deterministic final reduce: 16 tiles x 8 waves per batch element.
__global__ void pnl_ldet(const float* __restrict__ ws, float* __restrict__ outLd){
  const int b = threadIdx.x;
  float s = 0.f;
  #pragma unroll
  for (int t = 0; t < NTILE * 8; ++t) s += ws[b * NTILE * 8 + t];
  outLd[b] = s;
}

extern "C" void kernel_launch(void* const* d_in, const int* in_sizes, int n_in,
                              void* d_out, int out_size, void* d_ws, size_t ws_size,
                              hipStream_t stream){
  const float* x     = (const float*)d_in[0];
  const float* f1_hW = (const float*)d_in[1];
  const float* f1_hb = (const float*)d_in[2];
  const float* f1_oW = (const float*)d_in[3];
  const float* f1_ob = (const float*)d_in[4];
  const float* sW0   = (const float*)d_in[5];
  const float* sb0   = (const float*)d_in[6];
  const float* sW1   = (const float*)d_in[7];
  const float* sb1   = (const float*)d_in[8];
  const float* sW2   = (const float*)d_in[9];
  const float* sb2   = (const float*)d_in[10];
  const float* tW0   = (const float*)d_in[11];
  const float* tb0   = (const float*)d_in[12];
  const float* tW1   = (const float*)d_in[13];
  const float* tb1   = (const float*)d_in[14];
  const float* tW2   = (const float*)d_in[15];
  const float* tb2   = (const float*)d_in[16];

  char*  wsW    = (char*)d_ws;
  float* wsPart = (float*)(wsW + WSW_BYTES);          // 4096*8 floats
  float* resid  = (float*)d_out;
  float* outLd  = resid + (long)256 * TLr * Dd;

  pnl_conv<<<dim3(124), dim3(256), 0, stream>>>(sW0, sW1, sW2, tW0, tW1, tW2,
                                                f1_hW, f1_oW, wsW);
  pnl_main<<<dim3(256 * NTILE), dim3(NTHR), 0, stream>>>(
      x, f1_hb, f1_ob, sb0, sb1, sb2, tb0, tb1, tb2, wsW, resid, wsPart);
  pnl_ldet<<<dim3(1), dim3(256), 0, stream>>>(wsPart, outLd);
}

// Round 4
// 285.546 us; speedup vs baseline: 2.7569x; 1.6191x over previous
//
#include <hip/hip_runtime.h>

#define DEV __device__ __forceinline__

typedef __attribute__((ext_vector_type(8)))  short bf16x8;
typedef __attribute__((ext_vector_type(4)))  short s16x4;
typedef __attribute__((ext_vector_type(4)))  float f32x4;
typedef __attribute__((ext_vector_type(16))) float f32x16;
typedef __attribute__((ext_vector_type(4)))  unsigned u32x4;

constexpr int Tt = 1024, TLr = 1022;
constexpr long WSW_BYTES = 901120;   // preconverted fragment-linear weight image

#define MFMA32(a,b,c) __builtin_amdgcn_mfma_f32_32x32x16_bf16((a),(b),(c),0,0,0)

#define GLDS16(gp, lp) __builtin_amdgcn_global_load_lds( \
    (__attribute__((address_space(1))) void*)(void*)(gp), \
    (__attribute__((address_space(3))) void*)(void*)(lp), 16, 0, 0)

DEV short bf16hi(float f){
  unsigned u = __builtin_bit_cast(unsigned, f);
  u += 0x7FFFu + ((u >> 16) & 1u);          // round-to-nearest-even
  return (short)(u >> 16);
}
DEV float bf2f(short h){
  unsigned u = ((unsigned)(unsigned short)h) << 16;
  return __builtin_bit_cast(float, u);
}
DEV void splitbf(float f, short &h, short &l){
  h = bf16hi(f);
  l = bf16hi(f - bf2f(h));
}

DEV unsigned cvtpk(float a, float b){
  unsigned r;
  asm("v_cvt_pk_bf16_f32 %0, %1, %2" : "=v"(r) : "v"(a), "v"(b));
  return r;
}
DEV void plswap(unsigned &a, unsigned &b){
  auto r = __builtin_amdgcn_permlane32_swap((int)a, (int)b, false, false);
  a = (unsigned)r[0]; b = (unsigned)r[1];
}

// ACT: 0 none, 1 tanh, 2 relu, 3 leaky(0.2)
template<int A> DEV float actf(float x){
  if constexpr (A == 1){
    float e = __expf(2.f * x);
    return 1.f - 2.f * __builtin_amdgcn_rcpf(e + 1.f);
  } else if constexpr (A == 2){
    return fmaxf(x, 0.f);
  } else if constexpr (A == 3){
    return x >= 0.f ? x : 0.2f * x;
  }
  return x;
}

template<int BYTES>
DEV void pref(const char* __restrict__ wsW, long off, char* dst, int tid){
  #pragma unroll
  for (int it = 0; it < BYTES / 8192; ++it)
    GLDS16(wsW + off + it * 8192 + tid * 16, dst + it * 8192 + tid * 16);
}

// Convert one C m-tile (16 f32, feats 32m + (r&3)+8(r>>2)+4h) into next-layer
// B-fragment words for k-groups g0=2m (regs 0..7) and g1=2m+1 (regs 8..15).
// Word w of group g = bf16 pair (k = 16g + 8h + 2w, +1), h = lane>>5.
DEV void packTile(const f32x16& c, unsigned (&Bg0)[4], unsigned (&Bg1)[4]){
  unsigned p0 = cvtpk(c[0], c[1]),  p1 = cvtpk(c[2], c[3]);
  unsigned p2 = cvtpk(c[4], c[5]),  p3 = cvtpk(c[6], c[7]);
  plswap(p0, p2); plswap(p1, p3);
  Bg0[0] = p0; Bg0[1] = p1; Bg0[2] = p2; Bg0[3] = p3;
  p0 = cvtpk(c[8],  c[9]);  p1 = cvtpk(c[10], c[11]);
  p2 = cvtpk(c[12], c[13]); p3 = cvtpk(c[14], c[15]);
  plswap(p0, p2); plswap(p1, p3);
  Bg1[0] = p0; Bg1[1] = p1; Bg1[2] = p2; Bg1[3] = p3;
}

// Full 128-out layer, half-split over m (acc = 64 VGPR peak).
// Weights fragment-linear: block (kt*NMT + m), hi@+0 (lo@+1024 if LO).
template<int HI, int NMT, bool LO, int ACT>
DEV void bigLayer(const char* __restrict__ W, const float* __restrict__ bias,
                  const unsigned (&Bin)[2][8][4], unsigned (&Bout)[2][8][4],
                  int lane, int h4)
{
  constexpr int BS = LO ? 2048 : 1024;
  #pragma unroll
  for (int half = 0; half < 2; ++half){
    f32x16 acc[2][2];
    #pragma unroll
    for (int mi = 0; mi < 2; ++mi)
      #pragma unroll
      for (int n = 0; n < 2; ++n)
        #pragma unroll
        for (int i = 0; i < 16; ++i) acc[mi][n][i] = 0.f;
    #pragma unroll
    for (int kt = 0; kt < HI / 16; ++kt){
      #pragma unroll
      for (int mi = 0; mi < 2; ++mi){
        const char* wp = W + (kt * NMT + half * 2 + mi) * BS + lane * 16;
        bf16x8 Ah = *(const bf16x8*)wp;
        bf16x8 Al;
        if constexpr (LO) Al = *(const bf16x8*)(wp + 1024);
        #pragma unroll
        for (int n = 0; n < 2; ++n){
          u32x4 bw = {Bin[n][kt][0], Bin[n][kt][1], Bin[n][kt][2], Bin[n][kt][3]};
          bf16x8 B = __builtin_bit_cast(bf16x8, bw);
          acc[mi][n] = MFMA32(Ah, B, acc[mi][n]);
          if constexpr (LO) acc[mi][n] = MFMA32(Al, B, acc[mi][n]);
        }
      }
    }
    #pragma unroll
    for (int mi = 0; mi < 2; ++mi){
      const int m = half * 2 + mi;
      #pragma unroll
      for (int n = 0; n < 2; ++n){
        f32x16 &c = acc[mi][n];
        #pragma unroll
        for (int q = 0; q < 4; ++q){
          f32x4 bv = *(const f32x4*)(bias + 32 * m + 8 * q + h4);
          #pragma unroll
          for (int j = 0; j < 4; ++j)
            c[4 * q + j] = actf<ACT>(c[4 * q + j] + bv[j]);
        }
        packTile(c, Bout[n][2 * m], Bout[n][2 * m + 1]);
      }
    }
  }
}

// 64-out layer (NMT=2): output stays f32 in regs (bias added, no act).
template<int HI, int NMT, bool LO>
DEV void smallLayer(const char* __restrict__ W, const float* __restrict__ bias,
                    const unsigned (&Bin)[2][8][4], f32x16 (&out)[2][2],
                    int lane, int h4)
{
  constexpr int BS = LO ? 2048 : 1024;
  #pragma unroll
  for (int mi = 0; mi < 2; ++mi)
    #pragma unroll
    for (int n = 0; n < 2; ++n)
      #pragma unroll
      for (int i = 0; i < 16; ++i) out[mi][n][i] = 0.f;
  #pragma unroll
  for (int kt = 0; kt < HI / 16; ++kt){
    #pragma unroll
    for (int mi = 0; mi < 2; ++mi){
      const char* wp = W + (kt * NMT + mi) * BS + lane * 16;
      bf16x8 Ah = *(const bf16x8*)wp;
      bf16x8 Al;
      if constexpr (LO) Al = *(const bf16x8*)(wp + 1024);
      #pragma unroll
      for (int n = 0; n < 2; ++n){
        u32x4 bw = {Bin[n][kt][0], Bin[n][kt][1], Bin[n][kt][2], Bin[n][kt][3]};
        bf16x8 B = __builtin_bit_cast(bf16x8, bw);
        out[mi][n] = MFMA32(Ah, B, out[mi][n]);
        if constexpr (LO) out[mi][n] = MFMA32(Al, B, out[mi][n]);
      }
    }
  }
  #pragma unroll
  for (int mi = 0; mi < 2; ++mi)
    #pragma unroll
    for (int n = 0; n < 2; ++n)
      #pragma unroll
      for (int q = 0; q < 4; ++q){
        f32x4 bv = *(const f32x4*)(bias + 32 * mi + 8 * q + h4);
        #pragma unroll
        for (int j = 0; j < 4; ++j) out[mi][n][4 * q + j] += bv[j];
      }
}

// mx = u*mask -> B-fragment words (k-groups 0..3, K=64).
DEV void buildMaskedB(const f32x16 (&u)[2][2], unsigned (&B)[2][8][4], int keep){
  const float mOdd  = (keep == 1) ? 1.f : 0.f;
  const float mEven = 1.f - mOdd;
  #pragma unroll
  for (int mi = 0; mi < 2; ++mi)
    #pragma unroll
    for (int n = 0; n < 2; ++n){
      f32x16 v;
      #pragma unroll
      for (int r = 0; r < 16; ++r)
        v[r] = u[mi][n][r] * ((r & 1) ? mOdd : mEven);
      packTile(v, B[n][2 * mi], B[n][2 * mi + 1]);
    }
}

// f1 window input straight from global x into B-fragment words (128 k-feats).
DEV void buildWin(unsigned (&B)[2][8][4], const float* __restrict__ xb,
                  int rowW, int lane){
  const int col = lane & 31, h = lane >> 5;
  #pragma unroll
  for (int n = 0; n < 2; ++n){
    const int tau = rowW + n * 32 + col;
    #pragma unroll
    for (int g = 0; g < 8; ++g){
      int xr = tau + (g >= 4 ? 1 : 0);
      if (xr > Tt - 1) xr = Tt - 1;
      const int fo = (16 * g + 8 * h) & 63;
      const float* p = xb + xr * 64 + fo;
      f32x4 a = *(const f32x4*)p, b = *(const f32x4*)(p + 4);
      B[n][g][0] = cvtpk(a[0], a[1]); B[n][g][1] = cvtpk(a[2], a[3]);
      B[n][g][2] = cvtpk(b[0], b[1]); B[n][g][3] = cvtpk(b[2], b[3]);
    }
  }
}

// ---- Weight preconversion: fp32 -> 32x32-fragment-linear bf16 images ----
// flow blk b @ b*262144: s0@+0(32K) s1@+32768(64K) s2@+98304(32K)
//                        t0@+131072(32K) t1@+163840(64K) t2@+229376(32K)  [hi|lo]
// f1 (single bf16): h_i @786432+i*32768 (32K), oW @884736 (16K). Total 901120.
__global__ void pnl_conv(const float* __restrict__ sW0, const float* __restrict__ sW1,
                         const float* __restrict__ sW2, const float* __restrict__ tW0,
                         const float* __restrict__ tW1, const float* __restrict__ tW2,
                         const float* __restrict__ f1_hW, const float* __restrict__ f1_oW,
                         char* __restrict__ wsW)
{
  const int cid = blockIdx.x * 256 + threadIdx.x;    // 0..31743
  const float* src; long dst; int hs, NMT, unit; bool LO;
  if (cid < 24576){
    const int blk = cid >> 13, r = cid & 8191;
    const long b0 = (long)blk * 262144;
    if      (r < 1024){ src = sW0 + blk*8192;  hs = 6; NMT = 4; LO = true; unit = r;        dst = b0; }
    else if (r < 3072){ src = sW1 + blk*16384; hs = 7; NMT = 4; LO = true; unit = r - 1024; dst = b0 + 32768; }
    else if (r < 4096){ src = sW2 + blk*8192;  hs = 7; NMT = 2; LO = true; unit = r - 3072; dst = b0 + 98304; }
    else if (r < 5120){ src = tW0 + blk*8192;  hs = 6; NMT = 4; LO = true; unit = r - 4096; dst = b0 + 131072; }
    else if (r < 7168){ src = tW1 + blk*16384; hs = 7; NMT = 4; LO = true; unit = r - 5120; dst = b0 + 163840; }
    else              { src = tW2 + blk*8192;  hs = 7; NMT = 2; LO = true; unit = r - 7168; dst = b0 + 229376; }
  } else {
    const int r = cid - 24576;
    if (r < 6144){ const int l = r >> 11; src = f1_hW + l*16384; hs = 7; NMT = 4; LO = false; unit = r & 2047; dst = 786432 + (long)l*32768; }
    else         { src = f1_oW; hs = 7; NMT = 2; LO = false; unit = r - 6144; dst = 884736; }
  }
  const int e    = unit << 3;
  const int feat = e >> hs;
  const int k    = e & ((1 << hs) - 1);
  const int block = (k >> 4) * NMT + (feat >> 5);
  const int lane  = (feat & 31) | (((k >> 3) & 1) << 5);
  const long off  = dst + (long)block * (LO ? 2048 : 1024) + lane * 16;
  const float* sp = src + ((long)feat << hs) + k;
  f32x4 v0 = *(const f32x4*)sp, v1 = *(const f32x4*)(sp + 4);
  s16x4 ha, hb, la, lb;
  #pragma unroll
  for (int j = 0; j < 4; ++j){
    short hh, ll;
    splitbf(v0[j], hh, ll); ha[j] = hh; la[j] = ll;
    splitbf(v1[j], hh, ll); hb[j] = hh; lb[j] = ll;
  }
  *(s16x4*)(wsW + off)     = ha;
  *(s16x4*)(wsW + off + 8) = hb;
  if (LO){
    *(s16x4*)(wsW + off + 1024)     = la;
    *(s16x4*)(wsW + off + 1024 + 8) = lb;
  }
}

__global__ __launch_bounds__(512, 2)
void pnl_main(const float* __restrict__ x,
              const float* __restrict__ f1_hb, const float* __restrict__ f1_ob,
              const float* __restrict__ sb0, const float* __restrict__ sb1,
              const float* __restrict__ sb2, const float* __restrict__ tb0,
              const float* __restrict__ tb1, const float* __restrict__ tb2,
              const char* __restrict__ wsW,
              float* __restrict__ resid, float* __restrict__ wsPart)
{
  __shared__ __align__(16) char Wb[2][65536];   // weight double buffer only

  const int tid  = threadIdx.x, w = tid >> 6, lane = tid & 63;
  const int col  = lane & 31, h4 = (lane >> 5) * 4;
  const int bIdx = blockIdx.x >> 1;
  const int t0   = (blockIdx.x & 1) << 9;
  const int rowW = t0 + w * 64;                 // wave's first row (t index)
  const float* xb = x + (long)bIdx * Tt * 64;

  pref<32768>(wsW, 131072, Wb[0], tid);         // t0 of blk0

  // u init = x[b, tau+2, :] in C-fragment layout: uA[mi][n][r]
  f32x16 uA[2][2];
  #pragma unroll
  for (int mi = 0; mi < 2; ++mi)
    #pragma unroll
    for (int n = 0; n < 2; ++n){
      int xr = rowW + n * 32 + col + 2; if (xr > Tt - 1) xr = Tt - 1;
      #pragma unroll
      for (int q = 0; q < 4; ++q){
        f32x4 v = *(const f32x4*)(xb + xr * 64 + 32 * mi + 8 * q + h4);
        #pragma unroll
        for (int j = 0; j < 4; ++j) uA[mi][n][4 * q + j] = v[j];
      }
    }

  float ldet[2] = {0.f, 0.f};
  unsigned Bx[2][8][4], By[2][8][4];
  f32x16 stv[2][2];

  #pragma unroll 1
  for (int blk = 0; blk < 3; ++blk){
    const long base = (long)blk * 262144;
    const int keep = 1 - (blk & 1);             // blk0/2 keep odd feats

    buildMaskedB(uA, Bx, keep);
    __syncthreads();
    pref<65536>(wsW, base + 163840, Wb[1], tid);                    // t1
    bigLayer<64, 4, true, 2>(Wb[0], tb0 + blk * 128, Bx, By, lane, h4);   // t0
    __syncthreads();
    pref<32768>(wsW, base + 229376, Wb[0], tid);                    // t2
    bigLayer<128, 4, true, 2>(Wb[1], tb1 + blk * 128, By, Bx, lane, h4);  // t1
    __syncthreads();
    pref<32768>(wsW, base + 0, Wb[1], tid);                         // s0
    smallLayer<128, 2, true>(Wb[0], tb2 + blk * 64, Bx, stv, lane, h4);   // t2
    #pragma unroll
    for (int mi = 0; mi < 2; ++mi)
      #pragma unroll
      for (int n = 0; n < 2; ++n)
        #pragma unroll
        for (int r = 0; r < 16; ++r)
          if ((r & 1) != keep) uA[mi][n][r] -= stv[mi][n][r];       // u -= t
    buildMaskedB(uA, Bx, keep);
    __syncthreads();
    pref<65536>(wsW, base + 32768, Wb[0], tid);                     // s1
    bigLayer<64, 4, true, 1>(Wb[1], sb0 + blk * 128, Bx, By, lane, h4);   // s0
    __syncthreads();
    pref<32768>(wsW, base + 98304, Wb[1], tid);                     // s2
    bigLayer<128, 4, true, 1>(Wb[0], sb1 + blk * 128, By, Bx, lane, h4);  // s1
    __syncthreads();
    if (blk < 2) pref<32768>(wsW, base + 262144 + 131072, Wb[0], tid);    // next t0
    else         pref<32768>(wsW, 786432, Wb[0], tid);                    // f1h0
    smallLayer<128, 2, true>(Wb[1], sb2 + blk * 64, Bx, stv, lane, h4);   // s2
    #pragma unroll
    for (int mi = 0; mi < 2; ++mi)
      #pragma unroll
      for (int n = 0; n < 2; ++n)
        #pragma unroll
        for (int r = 0; r < 16; ++r)
          if ((r & 1) != keep){
            float e = __expf(-stv[mi][n][r]);
            uA[mi][n][r] *= e;                  // u = (u - t) * exp(-s)
            ldet[n] -= stv[mi][n][r];
          }
  }

  // ---- f1 sliding-window MLP (weights single bf16) ----
  buildWin(Bx, xb, rowW, lane);
  __syncthreads();
  pref<32768>(wsW, 819200, Wb[1], tid);                             // f1h1
  bigLayer<128, 4, false, 3>(Wb[0], f1_hb, Bx, By, lane, h4);
  __syncthreads();
  pref<32768>(wsW, 851968, Wb[0], tid);                             // f1h2
  bigLayer<128, 4, false, 3>(Wb[1], f1_hb + 128, By, Bx, lane, h4);
  __syncthreads();
  pref<16384>(wsW, 884736, Wb[1], tid);                             // f1o
  bigLayer<128, 4, false, 3>(Wb[0], f1_hb + 256, Bx, By, lane, h4);
  __syncthreads();
  smallLayer<128, 2, false>(Wb[1], f1_ob, By, stv, lane, h4);

  // residuals = f1(win) - x_inv (same fragment layout)
  #pragma unroll
  for (int mi = 0; mi < 2; ++mi)
    #pragma unroll
    for (int n = 0; n < 2; ++n){
      const int tau = rowW + n * 32 + col;
      if (tau < TLr){
        const long rb = ((long)bIdx * TLr + tau) * 64 + 32 * mi + h4;
        #pragma unroll
        for (int q = 0; q < 4; ++q){
          f32x4 st;
          #pragma unroll
          for (int j = 0; j < 4; ++j)
            st[j] = stv[mi][n][4 * q + j] - uA[mi][n][4 * q + j];
          *(f32x4*)(resid + rb + 8 * q) = st;
        }
      }
    }

  // logdet: each row's sum is split across lane pair (col, col+32);
  // full 64-lane butterfly sums every row exactly once.
  const int tau0 = rowW + col, tau1 = rowW + 32 + col;
  float s = (tau0 < TLr ? ldet[0] : 0.f) + (tau1 < TLr ? ldet[1] : 0.f);
  #pragma unroll
  for (int off = 1; off < 64; off <<= 1) s += __shfl_xor(s, off);
  if (lane == 0) wsPart[blockIdx.x * 8 + w] = s;
}

// Deterministic final reduce: 2 wgs x 8 waves per batch element.
__global__ void pnl_ldet(const float* __restrict__ ws, float* __restrict__ outLd){
  const int b = threadIdx.x;
  float s = 0.f;
  #pragma unroll
  for (int t = 0; t < 16; ++t) s += ws[b * 16 + t];
  outLd[b] = s;
}

extern "C" void kernel_launch(void* const* d_in, const int* in_sizes, int n_in,
                              void* d_out, int out_size, void* d_ws, size_t ws_size,
                              hipStream_t stream){
  const float* x     = (const float*)d_in[0];
  const float* f1_hW = (const float*)d_in[1];
  const float* f1_hb = (const float*)d_in[2];
  const float* f1_oW = (const float*)d_in[3];
  const float* f1_ob = (const float*)d_in[4];
  const float* sW0   = (const float*)d_in[5];
  const float* sb0   = (const float*)d_in[6];
  const float* sW1   = (const float*)d_in[7];
  const float* sb1   = (const float*)d_in[8];
  const float* sW2   = (const float*)d_in[9];
  const float* sb2   = (const float*)d_in[10];
  const float* tW0   = (const float*)d_in[11];
  const float* tb0   = (const float*)d_in[12];
  const float* tW1   = (const float*)d_in[13];
  const float* tb1   = (const float*)d_in[14];
  const float* tW2   = (const float*)d_in[15];
  const float* tb2   = (const float*)d_in[16];

  char*  wsW    = (char*)d_ws;
  float* wsPart = (float*)(wsW + WSW_BYTES);          // 512*8 floats
  float* resid  = (float*)d_out;
  float* outLd  = resid + (long)256 * TLr * 64;

  pnl_conv<<<dim3(124), dim3(256), 0, stream>>>(sW0, sW1, sW2, tW0, tW1, tW2,
                                                f1_hW, f1_oW, wsW);
  pnl_main<<<dim3(512), dim3(512), 0, stream>>>(
      x, f1_hb, f1_ob, sb0, sb1, sb2, tb0, tb1, tb2, wsW, resid, wsPart);
  pnl_ldet<<<dim3(1), dim3(256), 0, stream>>>(wsPart, outLd);
}